// Round 14
// baseline (1528.362 us; speedup 1.0000x reference)
//
#include <hip/hip_runtime.h>
#include <hip/hip_bf16.h>
#include <cstdint>

typedef __attribute__((ext_vector_type(8))) short s16x8;
typedef __attribute__((ext_vector_type(4))) short s16x4;
typedef __attribute__((ext_vector_type(2))) short s16x2;
typedef __attribute__((ext_vector_type(4))) float f32x4;

#define LTXT 256
#define LIMG 2048
#define LTOT 2304
#define HDIM 3072
#define NHEADS 24
#define HD 128
#define MLPD 12288

__device__ __forceinline__ short f2bf(float f) {
  union { float f; uint32_t u; } v; v.f = f;
  uint32_t r = v.u + 0x7FFFu + ((v.u >> 16) & 1u);
  return (short)(r >> 16);
}
__device__ __forceinline__ float bf2f(short s) {
  union { uint32_t u; float f; } v; v.u = ((uint32_t)(uint16_t)s) << 16;
  return v.f;
}

// async global->LDS, 16B per lane, wave-uniform LDS base + lane*16
#define GLDS16(gsrc, ldst)                                                   \
  __builtin_amdgcn_global_load_lds(                                          \
      (const __attribute__((address_space(1))) uint32_t*)(gsrc),             \
      (__attribute__((address_space(3))) uint32_t*)(ldst), 16, 0, 0)

// ---------------------------------------------------------------------------
// 1) mod GEMV
// ---------------------------------------------------------------------------
__global__ __launch_bounds__(256)
void mod_gemv(const float* __restrict__ vec,
              const float* __restrict__ w_img, const float* __restrict__ b_img,
              const float* __restrict__ w_txt, const float* __restrict__ b_txt,
              float* __restrict__ mod_img, float* __restrict__ mod_txt)
{
  __shared__ float sv[HDIM];
  const int t = threadIdx.x;
  for (int i = t; i < HDIM; i += 256) {
    float x = vec[i];
    sv[i] = x / (1.f + __expf(-x));
  }
  __syncthreads();
  const float* w = blockIdx.y ? w_txt : w_img;
  const float* bb = blockIdx.y ? b_txt : b_img;
  float* o = blockIdx.y ? mod_txt : mod_img;
  const int lane = t & 63, kc = t >> 6;
  const int colbase = blockIdx.x * 256 + lane * 4;
  f32x4 acc = {0.f, 0.f, 0.f, 0.f};
  const float* wp = w + (size_t)kc * 768 * 18432 + colbase;
  #pragma unroll 4
  for (int k = 0; k < 768; ++k) {
    float4 wv = *(const float4*)wp;
    float s = sv[kc * 768 + k];
    acc[0] += s * wv.x; acc[1] += s * wv.y;
    acc[2] += s * wv.z; acc[3] += s * wv.w;
    wp += 18432;
  }
  __shared__ f32x4 part[4][64];
  part[kc][lane] = acc;
  __syncthreads();
  if (t < 64) {
    f32x4 r = part[0][t];
    #pragma unroll
    for (int c = 1; c < 4; ++c) r += part[c][t];
    int cb = blockIdx.x * 256 + t * 4;
    float4 bv = *(const float4*)(bb + cb);
    float4 ov; ov.x = r[0] + bv.x; ov.y = r[1] + bv.y;
    ov.z = r[2] + bv.z; ov.w = r[3] + bv.w;
    *(float4*)(o + cb) = ov;
  }
}

// ---------------------------------------------------------------------------
// 2/8) LayerNorm + modulate
// ---------------------------------------------------------------------------
__global__ __launch_bounds__(256)
void ln_mod(const float* __restrict__ xi, const float* __restrict__ xt, int rows_img,
            const float* __restrict__ si, const float* __restrict__ bi,
            const float* __restrict__ st, const float* __restrict__ bt,
            const float* __restrict__ modi, const float* __restrict__ modt,
            int sh_chunk, int sc_chunk,
            short* __restrict__ oi, short* __restrict__ ot)
{
  const int row = blockIdx.x;
  const float *x, *s, *b, *mod;
  short* out;
  if (row < rows_img) {
    x = xi + (size_t)row * HDIM; s = si; b = bi; mod = modi;
    out = oi + (size_t)row * HDIM;
  } else {
    int lr = row - rows_img;
    x = xt + (size_t)lr * HDIM; s = st; b = bt; mod = modt;
    out = ot + (size_t)lr * HDIM;
  }
  const float* sh = mod + (size_t)sh_chunk * HDIM;
  const float* sc = mod + (size_t)sc_chunk * HDIM;
  const int t = threadIdx.x;
  float xv[12];
  {
    float4 a = *(const float4*)(x + t * 12 + 0);
    float4 c = *(const float4*)(x + t * 12 + 4);
    float4 d = *(const float4*)(x + t * 12 + 8);
    xv[0]=a.x; xv[1]=a.y; xv[2]=a.z; xv[3]=a.w;
    xv[4]=c.x; xv[5]=c.y; xv[6]=c.z; xv[7]=c.w;
    xv[8]=d.x; xv[9]=d.y; xv[10]=d.z; xv[11]=d.w;
  }
  float sum = 0.f, ss = 0.f;
  #pragma unroll
  for (int e = 0; e < 12; ++e) { sum += xv[e]; ss += xv[e] * xv[e]; }
  for (int xm = 1; xm < 64; xm <<= 1) {
    sum += __shfl_xor(sum, xm);
    ss  += __shfl_xor(ss, xm);
  }
  __shared__ float red[8];
  const int w = t >> 6, lane = t & 63;
  if (lane == 0) { red[w] = sum; red[4 + w] = ss; }
  __syncthreads();
  sum = red[0] + red[1] + red[2] + red[3];
  ss  = red[4] + red[5] + red[6] + red[7];
  const float mean = sum * (1.f / HDIM);
  const float var = ss * (1.f / HDIM) - mean * mean;
  const float rs = rsqrtf(var + 1e-6f);
  short ov[12];
  #pragma unroll
  for (int e = 0; e < 12; ++e) {
    int c = t * 12 + e;
    float y = (xv[e] - mean) * rs * s[c] + b[c];
    ov[e] = f2bf((1.f + sc[c]) * y + sh[c]);
  }
  #pragma unroll
  for (int j = 0; j < 3; ++j) {
    s16x4 v = { ov[j*4+0], ov[j*4+1], ov[j*4+2], ov[j*4+3] };
    *(s16x4*)(out + t * 12 + j * 4) = v;
  }
}

// ---------------------------------------------------------------------------
// Fused GEMM 128x128x64, double-buffered 2-phase pipeline with inline
// fp32->bf16 weight conversion (T14 issue-early/write-late):
//   stageA(t+1) glds  +  issue 32 coalesced fp32 W loads(t+1) -> regs
//   -> MFMA(t)  ->  cvt+4x ds_write_b128(t+1) (R8 mapping, 0 conflicts)
//   -> vmcnt(0)+lgkmcnt(0)+barrier.
// XCD remap bm-fastest (W panel L2-resident per XCD).
// C[M,N] = epi(A_bf16[M,K] @ W_f32[K,N] + bias)
// EPI: 0 = store bf16; 1 = gelu->bf16; 2 = f32: resid + gate*x; 3 = f32: += gate*x
// ---------------------------------------------------------------------------
template<int EPI>
__global__ __launch_bounds__(256, 2)
void gemmF(const short* __restrict__ A, int K, int N, int split,
           const float* __restrict__ W0, const float* __restrict__ W1,
           const float* __restrict__ b0, const float* __restrict__ b1,
           void* __restrict__ out0, void* __restrict__ out1,
           const float* __restrict__ r0, const float* __restrict__ r1,
           const float* __restrict__ g0, const float* __restrict__ g1)
{
  __shared__ __align__(16) short lds[2][16384];  // per buf: A @0, B @8192
  const int tid = threadIdx.x;
  const int lane = tid & 63, w = tid >> 6;
  const int wr = w >> 1, wc = w & 1;
  const int l15 = lane & 15, lg = lane >> 4;

  // XCD-aware bijective remap (m204), M-tile fastest
  const int gx = gridDim.x;
  const int nwg = gx * gridDim.y;
  const int lin = blockIdx.y * gx + blockIdx.x;
  const int q8 = nwg >> 3, r8 = nwg & 7;
  const int xcd = lin & 7, loc = lin >> 3;
  const int nid = (xcd < r8 ? xcd * (q8 + 1) : r8 * (q8 + 1) + (xcd - r8) * q8) + loc;
  const int bm = nid % gx, bn = nid / gx;

  const bool is1 = bm >= split;
  const int m0 = bm * 128, n0 = bn * 128;
  const float* Wf = is1 ? W1 : W0;
  const float* bias = is1 ? b1 : b0;
  const int nt = K >> 6;

  f32x4 acc[4][4];
  #pragma unroll
  for (int i = 0; i < 4; ++i)
    #pragma unroll
    for (int j = 0; j < 4; ++j)
      acc[i][j] = f32x4{0.f, 0.f, 0.f, 0.f};

  const int srow_b = w * 8 + (lane >> 3);     // + rep*32
  const int x7 = lane & 7;
  const int nB = tid & 127;                   // owned B n-row
  const int obB = (tid >> 7) * 4;             // owned B octet base (0 or 4)
  const float* WfB = Wf + n0 + nB;

  auto stageA = [&](int tt, int b) {
    const size_t kk = (size_t)tt * 64;
    #pragma unroll
    for (int rep = 0; rep < 4; ++rep) {
      const int row = rep * 32 + srow_b;
      const int lc = x7 ^ (row & 7);
      GLDS16(A + (size_t)(m0 + row) * K + kk + lc * 8, &lds[b][rep * 2048 + w * 512]);
    }
  };
  float fb[4][8];
  auto loadB = [&](int tt) {
    const float* wp = WfB + (size_t)(tt * 64 + obB * 8) * N;
    #pragma unroll
    for (int oi = 0; oi < 4; ++oi)
      #pragma unroll
      for (int i = 0; i < 8; ++i)
        fb[oi][i] = wp[(size_t)(oi * 8 + i) * N];
  };
  auto writeB = [&](int b) {
    #pragma unroll
    for (int oi = 0; oi < 4; ++oi) {
      const int o = obB + oi;
      s16x8 p;
      #pragma unroll
      for (int i = 0; i < 8; ++i) p[i] = f2bf(fb[oi][i]);
      *(s16x8*)(&lds[b][8192 + nB * 64 + ((o ^ (nB & 7)) * 8)]) = p;
    }
  };

  // prologue: tile 0
  stageA(0, 0);
  loadB(0);
  writeB(0);
  asm volatile("s_waitcnt vmcnt(0) lgkmcnt(0)" ::: "memory");
  __builtin_amdgcn_s_barrier();

  for (int t = 0; t < nt; ++t) {
    const int cur = t & 1;
    if (t + 1 < nt) {
      stageA(t + 1, cur ^ 1);   // async A
      loadB(t + 1);             // fp32 W loads issue early, land during MFMA
    }
    const short* base = &lds[cur][0];
    #pragma unroll
    for (int ks = 0; ks < 2; ++ks) {
      const int cofs = ((ks * 4 + lg) ^ (l15 & 7)) * 8;
      s16x8 av[4], bv[4];
      #pragma unroll
      for (int mf = 0; mf < 4; ++mf)
        av[mf] = *(const s16x8*)(base + (wr * 64 + mf * 16 + l15) * 64 + cofs);
      #pragma unroll
      for (int nf = 0; nf < 4; ++nf)
        bv[nf] = *(const s16x8*)(base + 8192 + (wc * 64 + nf * 16 + l15) * 64 + cofs);
      __builtin_amdgcn_s_setprio(1);
      #pragma unroll
      for (int mf = 0; mf < 4; ++mf)
        #pragma unroll
        for (int nf = 0; nf < 4; ++nf)
          acc[mf][nf] = __builtin_amdgcn_mfma_f32_16x16x32_bf16(
              av[mf], bv[nf], acc[mf][nf], 0, 0, 0);
      __builtin_amdgcn_s_setprio(0);
    }
    if (t + 1 < nt) {
      writeB(cur ^ 1);          // cvt + conflict-free b128 writes
      asm volatile("s_waitcnt vmcnt(0) lgkmcnt(0)" ::: "memory");
      __builtin_amdgcn_s_barrier();
    }
  }

  // epilogue: C frag layout col=lane&15, row=(lane>>4)*4+reg
  const int lrbase = m0 - (is1 ? split * 128 : 0);
  #pragma unroll
  for (int mf = 0; mf < 4; ++mf)
    #pragma unroll
    for (int nf = 0; nf < 4; ++nf) {
      int col = n0 + wc * 64 + nf * 16 + l15;
      float bvs = bias[col];
      #pragma unroll
      for (int r = 0; r < 4; ++r) {
        int row = lrbase + wr * 64 + mf * 16 + lg * 4 + r;
        float x = acc[mf][nf][r] + bvs;
        if constexpr (EPI == 0) {
          short* o = (short*)(is1 ? out1 : out0);
          o[(size_t)row * N + col] = f2bf(x);
        } else if constexpr (EPI == 1) {
          float g = 0.5f * x * (1.f + tanhf(0.7978845608028654f * (x + 0.044715f * x * x * x)));
          short* o = (short*)(is1 ? out1 : out0);
          o[(size_t)row * N + col] = f2bf(g);
        } else if constexpr (EPI == 2) {
          const float* resid = is1 ? r1 : r0;
          const float* gate = is1 ? g1 : g0;
          float* o = (float*)(is1 ? out1 : out0);
          o[(size_t)row * N + col] = resid[(size_t)row * N + col] + gate[col] * x;
        } else {
          const float* gate = is1 ? g1 : g0;
          float* o = (float*)(is1 ? out1 : out0);
          size_t ix = (size_t)row * N + col;
          o[ix] = o[ix] + gate[col] * x;
        }
      }
    }
}

// ---------------------------------------------------------------------------
// 4) per-(token, head) RMS norm + RoPE for q,k -> [NH][LTOT][HD] bf16
// ---------------------------------------------------------------------------
__global__ __launch_bounds__(256)
void qkvr(const short* __restrict__ qkv, const float* __restrict__ pe,
          const float* __restrict__ qn_img, const float* __restrict__ kn_img,
          const float* __restrict__ qn_txt, const float* __restrict__ kn_txt,
          short* __restrict__ Qh, short* __restrict__ Kh)
{
  const int w = threadIdx.x >> 6, lane = threadIdx.x & 63;
  const int tok = blockIdx.x * 4 + w;
  const int h = blockIdx.y;
  const float* qn = (tok < LTXT) ? qn_txt : qn_img;
  const float* kn = (tok < LTXT) ? kn_txt : kn_img;
  const size_t base = (size_t)tok * 9216 + (size_t)h * HD + lane * 2;
  const float4 p4 = *(const float4*)(pe + ((size_t)tok * 64 + lane) * 4);
  {
    s16x2 qs = *(const s16x2*)(qkv + base);
    float x0 = bf2f(qs[0]), x1 = bf2f(qs[1]);
    float sq = x0 * x0 + x1 * x1;
    for (int xm = 1; xm < 64; xm <<= 1) sq += __shfl_xor(sq, xm);
    float r = rsqrtf(sq * (1.f / HD) + 1e-6f);
    x0 = x0 * r * qn[lane * 2]; x1 = x1 * r * qn[lane * 2 + 1];
    s16x2 o = { f2bf(p4.x * x0 + p4.y * x1), f2bf(p4.z * x0 + p4.w * x1) };
    *(s16x2*)(Qh + ((size_t)h * LTOT + tok) * HD + lane * 2) = o;
  }
  {
    s16x2 ks = *(const s16x2*)(qkv + base + HDIM);
    float x0 = bf2f(ks[0]), x1 = bf2f(ks[1]);
    float sq = x0 * x0 + x1 * x1;
    for (int xm = 1; xm < 64; xm <<= 1) sq += __shfl_xor(sq, xm);
    float r = rsqrtf(sq * (1.f / HD) + 1e-6f);
    x0 = x0 * r * kn[lane * 2]; x1 = x1 * r * kn[lane * 2 + 1];
    s16x2 o = { f2bf(p4.x * x0 + p4.y * x1), f2bf(p4.z * x0 + p4.w * x1) };
    *(s16x2*)(Kh + ((size_t)h * LTOT + tok) * HD + lane * 2) = o;
  }
}

// ---------------------------------------------------------------------------
// 5) V transpose: qkv v-slice -> VT[NH][HD][LTOT] bf16. grid (LTOT/64, NH).
// ---------------------------------------------------------------------------
__global__ __launch_bounds__(256)
void vt_k(const short* __restrict__ qkv, short* __restrict__ VT)
{
  __shared__ __align__(16) short Vs[64][136];
  const int h = blockIdx.y, tok0 = blockIdx.x * 64;
  const int t = threadIdx.x;
  #pragma unroll
  for (int rep = 0; rep < 4; ++rep) {
    int idx = rep * 256 + t;
    int tk = idx >> 4, oct = idx & 15;
    *(s16x8*)(&Vs[tk][oct * 8]) =
        *(const s16x8*)(qkv + (size_t)(tok0 + tk) * 9216 + 6144 + (size_t)h * HD + oct * 8);
  }
  __syncthreads();
  #pragma unroll
  for (int rep = 0; rep < 4; ++rep) {
    int idx = rep * 256 + t;
    int d = idx >> 3, tg = idx & 7;
    s16x8 o;
    #pragma unroll
    for (int j = 0; j < 8; ++j) o[j] = Vs[tg * 8 + j][d];
    *(s16x8*)(VT + ((size_t)h * HD + d) * LTOT + tok0 + tg * 8) = o;
  }
}

// ---------------------------------------------------------------------------
// 6) Flash attention, static softmax + cooperative K staging (R12 config).
// ---------------------------------------------------------------------------
__global__ __launch_bounds__(256, 3)
void attn_k(const short* __restrict__ Qh, const short* __restrict__ Kh,
            const short* __restrict__ VT, short* __restrict__ out)
{
  __shared__ __align__(16) short Ks[2][8192];   // [buf][64 keys][128 d] swizzled
  __shared__ __align__(16) short Ps[4][32][72];
  const int t = threadIdx.x, lane = t & 63, w = t >> 6;
  const int l15 = lane & 15, lg = lane >> 4;
  const int lin = blockIdx.y * gridDim.x + blockIdx.x;
  const int xcd = lin & 7, j = lin >> 3;
  const int h = xcd * 3 + j / 18;
  const int qrow = (j % 18) * 128 + w * 32;

  s16x8 qf[2][4];
  #pragma unroll
  for (int mf = 0; mf < 2; ++mf)
    #pragma unroll
    for (int ks = 0; ks < 4; ++ks)
      qf[mf][ks] = *(const s16x8*)(Qh + ((size_t)h * LTOT + qrow + mf * 16 + l15) * HD + ks * 32 + lg * 8);

  f32x4 O[2][8];
  #pragma unroll
  for (int mf = 0; mf < 2; ++mf)
    #pragma unroll
    for (int dt = 0; dt < 8; ++dt) O[mf][dt] = f32x4{0.f, 0.f, 0.f, 0.f};
  f32x4 den[2];
  den[0] = f32x4{0.f, 0.f, 0.f, 0.f};
  den[1] = f32x4{0.f, 0.f, 0.f, 0.f};

  const float scl = 0.08838834764831845f;  // 1/sqrt(128)

  auto stageK = [&](int kt, int b) {
    const int k0 = kt * 64;
    #pragma unroll
    for (int it = 0; it < 4; ++it) {
      const int idx = it * 256 + w * 64 + lane;
      const int row = idx >> 4, p = idx & 15;
      const int l = p ^ (row & 15);
      GLDS16(Kh + ((size_t)h * LTOT + k0 + row) * HD + l * 8,
             &Ks[b][(it * 256 + w * 64) * 8]);
    }
  };

  stageK(0, 0);
  asm volatile("s_waitcnt vmcnt(0)" ::: "memory");
  __builtin_amdgcn_s_barrier();

  for (int kt = 0; kt < LTOT / 64; ++kt) {
    const int k0 = kt * 64;
    const int b = kt & 1;
    if (kt + 1 < LTOT / 64) stageK(kt + 1, b ^ 1);
    f32x4 S[2][4];
    #pragma unroll
    for (int mf = 0; mf < 2; ++mf)
      #pragma unroll
      for (int jt = 0; jt < 4; ++jt) S[mf][jt] = f32x4{0.f, 0.f, 0.f, 0.f};
    #pragma unroll
    for (int ks = 0; ks < 4; ++ks)
      #pragma unroll
      for (int jt = 0; jt < 4; ++jt) {
        const int row = jt * 16 + l15;
        s16x8 kf = *(const s16x8*)(&Ks[b][row * 128 + ((ks * 4 + lg) ^ l15) * 8]);
        S[0][jt] = __builtin_amdgcn_mfma_f32_16x16x32_bf16(qf[0][ks], kf, S[0][jt], 0, 0, 0);
        S[1][jt] = __builtin_amdgcn_mfma_f32_16x16x32_bf16(qf[1][ks], kf, S[1][jt], 0, 0, 0);
      }
    #pragma unroll
    for (int mf = 0; mf < 2; ++mf)
      #pragma unroll
      for (int jt = 0; jt < 4; ++jt)
        #pragma unroll
        for (int r = 0; r < 4; ++r) {
          float p = __expf(S[mf][jt][r] * scl);
          den[mf][r] += p;
          Ps[w][mf * 16 + lg * 4 + r][jt * 16 + l15] = f2bf(p);
        }
    asm volatile("s_waitcnt lgkmcnt(0)" ::: "memory");
    __builtin_amdgcn_sched_barrier(0);
    #pragma unroll
    for (int kk2 = 0; kk2 < 2; ++kk2) {
      s16x8 pf0 = *(const s16x8*)(&Ps[w][l15][kk2 * 32 + lg * 8]);
      s16x8 pf1 = *(const s16x8*)(&Ps[w][16 + l15][kk2 * 32 + lg * 8]);
      #pragma unroll
      for (int dt = 0; dt < 8; ++dt) {
        s16x8 vf = *(const s16x8*)(VT + ((size_t)h * HD + dt * 16 + l15) * LTOT + k0 + kk2 * 32 + lg * 8);
        O[0][dt] = __builtin_amdgcn_mfma_f32_16x16x32_bf16(pf0, vf, O[0][dt], 0, 0, 0);
        O[1][dt] = __builtin_amdgcn_mfma_f32_16x16x32_bf16(pf1, vf, O[1][dt], 0, 0, 0);
      }
    }
    asm volatile("s_waitcnt lgkmcnt(0)" ::: "memory");
    __builtin_amdgcn_sched_barrier(0);
    asm volatile("s_waitcnt vmcnt(0)" ::: "memory");
    __builtin_amdgcn_s_barrier();
  }

  #pragma unroll
  for (int mf = 0; mf < 2; ++mf)
    for (int xm = 1; xm < 16; xm <<= 1)
      #pragma unroll
      for (int r = 0; r < 4; ++r)
        den[mf][r] += __shfl_xor(den[mf][r], xm);

  #pragma unroll
  for (int mf = 0; mf < 2; ++mf) {
    f32x4 inv;
    #pragma unroll
    for (int r = 0; r < 4; ++r) inv[r] = 1.f / den[mf][r];
    #pragma unroll
    for (int dt = 0; dt < 8; ++dt) {
      f32x4 o = O[mf][dt] * inv;
      #pragma unroll
      for (int r = 0; r < 4; ++r)
        out[(size_t)(qrow + mf * 16 + lg * 4 + r) * HDIM + (size_t)h * HD + dt * 16 + l15] = f2bf(o[r]);
    }
  }
}

// ---------------------------------------------------------------------------
extern "C" void kernel_launch(void* const* d_in, const int* in_sizes, int n_in,
                              void* d_out, int out_size, void* d_ws, size_t ws_size,
                              hipStream_t stream)
{
  (void)in_sizes; (void)n_in; (void)out_size;
  const float* img = (const float*)d_in[0];
  const float* txt = (const float*)d_in[1];
  const float* vec = (const float*)d_in[2];
  const float* pe  = (const float*)d_in[3];
  const float* Pi[16]; const float* Pt[16];
  for (int i = 0; i < 16; ++i) Pi[i] = (const float*)d_in[4 + i];
  for (int i = 0; i < 16; ++i) Pt[i] = (const float*)d_in[20 + i];
  // 0 mod_w,1 mod_b,2 ln1_s,3 ln1_b,4 qkv_w,5 qkv_b,6 qn,7 kn,8 proj_w,
  // 9 proj_b,10 ln2_s,11 ln2_b,12 mlp_w1,13 mlp_b1,14 mlp_w2,15 mlp_b2

  char* ws = (char*)d_ws;
  float* MODI = (float*)(ws + 0);
  float* MODT = (float*)(ws + 73728);
  short* XMI  = (short*)(ws + 147456);        // [2304][3072] bf16 img-first
  short* XMT  = (short*)(ws + 12730368);
  short* QKV  = (short*)(ws + 14303232);      // [2304][9216] bf16, txt-first rows
  short* QHh  = (short*)(ws + 56770560);      // [24][2304][128]
  short* KHh  = (short*)(ws + 70926336);
  short* VTt  = (short*)(ws + 85082112);      // [24][128][2304]
  short* ATT  = (short*)(ws + 99237888);      // [2304][3072] txt-first rows
  short* H1   = (short*)(ws + 14303232);      // reuse QKV+QH region: [2304][12288] img-first
  if (ws_size < (size_t)113393664) return;
  float* outI = (float*)d_out;
  float* outT = outI + (size_t)LIMG * HDIM;

  // 1) modulation vectors
  mod_gemv<<<dim3(72, 2), 256, 0, stream>>>(vec, Pi[0], Pi[1], Pt[0], Pt[1], MODI, MODT);
  // 2) LN1 + modulate
  ln_mod<<<dim3(LTOT), 256, 0, stream>>>(img, txt, LIMG, Pi[2], Pi[3], Pt[2], Pt[3],
                                         MODI, MODT, 0, 1, XMI, XMT);
  // 3) QKV (fp32 weights converted inline, split=16)
  gemmF<0><<<dim3(18, 72), 256, 0, stream>>>(XMI, HDIM, 3 * HDIM, 16,
      Pi[4], Pt[4], Pi[5], Pt[5],
      QKV + (size_t)LTXT * 9216, QKV, nullptr, nullptr, nullptr, nullptr);
  // 4) RMS + RoPE
  qkvr<<<dim3(LTOT / 4, NHEADS), 256, 0, stream>>>(QKV, pe, Pi[6], Pi[7], Pt[6], Pt[7], QHh, KHh);
  // 5) V transpose
  vt_k<<<dim3(LTOT / 64, NHEADS), 256, 0, stream>>>(QKV, VTt);
  // 6) attention (head-grouped XCD mapping, static softmax, K staged)
  attn_k<<<dim3(18, 24), 256, 0, stream>>>(QHh, KHh, VTt, ATT);
  // 7) proj + gated residual -> d_out (ATT txt-first, split=2: stream0=txt)
  gemmF<2><<<dim3(18, 24), 256, 0, stream>>>(ATT, HDIM, HDIM, 2,
      Pt[8], Pi[8], Pt[9], Pi[9], outT, outI, txt, img,
      MODT + 2 * HDIM, MODI + 2 * HDIM);
  // 8) LN2 + modulate
  ln_mod<<<dim3(LTOT), 256, 0, stream>>>(outI, outT, LIMG, Pi[10], Pi[11], Pt[10], Pt[11],
                                         MODI, MODT, 3, 4, XMI, XMT);
  // 9) MLP1 + gelu (split=16) -> H1 img-first
  gemmF<1><<<dim3(18, 96), 256, 0, stream>>>(XMI, HDIM, MLPD, 16,
      Pi[12], Pt[12], Pi[13], Pt[13],
      H1, H1 + (size_t)LIMG * MLPD, nullptr, nullptr, nullptr, nullptr);
  // 10) MLP2 + gated residual add (split=16)
  gemmF<3><<<dim3(18, 24), 256, 0, stream>>>(H1, MLPD, HDIM, 16,
      Pi[14], Pt[14], Pi[15], Pt[15], outI, outT, nullptr, nullptr,
      MODI + 5 * HDIM, MODT + 5 * HDIM);
}

// Round 15
// 1348.362 us; speedup vs baseline: 1.1335x; 1.1335x over previous
//
#include <hip/hip_runtime.h>
#include <hip/hip_bf16.h>
#include <cstdint>

typedef __attribute__((ext_vector_type(8))) short s16x8;
typedef __attribute__((ext_vector_type(4))) short s16x4;
typedef __attribute__((ext_vector_type(2))) short s16x2;
typedef __attribute__((ext_vector_type(4))) float f32x4;

#define LTXT 256
#define LIMG 2048
#define LTOT 2304
#define HDIM 3072
#define NHEADS 24
#define HD 128
#define MLPD 12288

__device__ __forceinline__ short f2bf(float f) {
  union { float f; uint32_t u; } v; v.f = f;
  uint32_t r = v.u + 0x7FFFu + ((v.u >> 16) & 1u);
  return (short)(r >> 16);
}
__device__ __forceinline__ float bf2f(short s) {
  union { uint32_t u; float f; } v; v.u = ((uint32_t)(uint16_t)s) << 16;
  return v.f;
}

// async global->LDS, 16B per lane, wave-uniform LDS base + lane*16
#define GLDS16(gsrc, ldst)                                                   \
  __builtin_amdgcn_global_load_lds(                                          \
      (const __attribute__((address_space(1))) uint32_t*)(gsrc),             \
      (__attribute__((address_space(3))) uint32_t*)(ldst), 16, 0, 0)

// ---------------------------------------------------------------------------
// 0) weight convert+transpose: Wf fp32 [K][N] -> Wt bf16 [N][K]
// blockIdx.z picks (src,dst) pair so img+txt convert in one dispatch.
// ---------------------------------------------------------------------------
__global__ __launch_bounds__(256)
void wconv2(const float* __restrict__ Wf0, short* __restrict__ Wt0,
            const float* __restrict__ Wf1, short* __restrict__ Wt1, int K, int N)
{
  const float* Wf = blockIdx.z ? Wf1 : Wf0;
  short* Wt = blockIdx.z ? Wt1 : Wt0;
  __shared__ short Ls[64][68];
  const int t = threadIdx.x;
  const int k0 = blockIdx.x * 64, n0 = blockIdx.y * 64;
  #pragma unroll
  for (int rep = 0; rep < 4; ++rep) {
    int idx = rep * 256 + t;
    int k = idx >> 4;
    int n = (idx & 15) * 4;
    float4 v = *(const float4*)(Wf + (size_t)(k0 + k) * N + n0 + n);
    Ls[k][n + 0] = f2bf(v.x); Ls[k][n + 1] = f2bf(v.y);
    Ls[k][n + 2] = f2bf(v.z); Ls[k][n + 3] = f2bf(v.w);
  }
  __syncthreads();
  #pragma unroll
  for (int rep = 0; rep < 4; ++rep) {
    int idx = rep * 256 + t;
    int n = idx >> 4;
    int k = (idx & 15) * 4;
    s16x4 o = { Ls[k + 0][n], Ls[k + 1][n], Ls[k + 2][n], Ls[k + 3][n] };
    *(s16x4*)(Wt + (size_t)(n0 + n) * K + k0 + k) = o;
  }
}

// ---------------------------------------------------------------------------
// 1) mod GEMV: 128 cols/block (float2 per lane), 288 blocks -> BW-saturating.
// ---------------------------------------------------------------------------
__global__ __launch_bounds__(256)
void mod_gemv(const float* __restrict__ vec,
              const float* __restrict__ w_img, const float* __restrict__ b_img,
              const float* __restrict__ w_txt, const float* __restrict__ b_txt,
              float* __restrict__ mod_img, float* __restrict__ mod_txt)
{
  __shared__ float sv[HDIM];
  const int t = threadIdx.x;
  for (int i = t; i < HDIM; i += 256) {
    float x = vec[i];
    sv[i] = x / (1.f + __expf(-x));
  }
  __syncthreads();
  const float* w = blockIdx.y ? w_txt : w_img;
  const float* bb = blockIdx.y ? b_txt : b_img;
  float* o = blockIdx.y ? mod_txt : mod_img;
  const int lane = t & 63, kc = t >> 6;
  const int colbase = blockIdx.x * 128 + lane * 2;
  float a0 = 0.f, a1 = 0.f;
  const float* wp = w + (size_t)kc * 768 * 18432 + colbase;
  #pragma unroll 4
  for (int k = 0; k < 768; ++k) {
    float2 wv = *(const float2*)wp;
    float s = sv[kc * 768 + k];
    a0 += s * wv.x; a1 += s * wv.y;
    wp += 18432;
  }
  __shared__ float2 part[4][64];
  part[kc][lane] = make_float2(a0, a1);
  __syncthreads();
  if (t < 64) {
    float2 r = part[0][t];
    #pragma unroll
    for (int c = 1; c < 4; ++c) { r.x += part[c][t].x; r.y += part[c][t].y; }
    int cb = blockIdx.x * 128 + t * 2;
    float2 bv = *(const float2*)(bb + cb);
    float2 ov; ov.x = r.x + bv.x; ov.y = r.y + bv.y;
    *(float2*)(o + cb) = ov;
  }
}

// ---------------------------------------------------------------------------
// 2/8) LayerNorm + modulate
// ---------------------------------------------------------------------------
__global__ __launch_bounds__(256)
void ln_mod(const float* __restrict__ xi, const float* __restrict__ xt, int rows_img,
            const float* __restrict__ si, const float* __restrict__ bi,
            const float* __restrict__ st, const float* __restrict__ bt,
            const float* __restrict__ modi, const float* __restrict__ modt,
            int sh_chunk, int sc_chunk,
            short* __restrict__ oi, short* __restrict__ ot)
{
  const int row = blockIdx.x;
  const float *x, *s, *b, *mod;
  short* out;
  if (row < rows_img) {
    x = xi + (size_t)row * HDIM; s = si; b = bi; mod = modi;
    out = oi + (size_t)row * HDIM;
  } else {
    int lr = row - rows_img;
    x = xt + (size_t)lr * HDIM; s = st; b = bt; mod = modt;
    out = ot + (size_t)lr * HDIM;
  }
  const float* sh = mod + (size_t)sh_chunk * HDIM;
  const float* sc = mod + (size_t)sc_chunk * HDIM;
  const int t = threadIdx.x;
  float xv[12];
  {
    float4 a = *(const float4*)(x + t * 12 + 0);
    float4 c = *(const float4*)(x + t * 12 + 4);
    float4 d = *(const float4*)(x + t * 12 + 8);
    xv[0]=a.x; xv[1]=a.y; xv[2]=a.z; xv[3]=a.w;
    xv[4]=c.x; xv[5]=c.y; xv[6]=c.z; xv[7]=c.w;
    xv[8]=d.x; xv[9]=d.y; xv[10]=d.z; xv[11]=d.w;
  }
  float sum = 0.f, ss = 0.f;
  #pragma unroll
  for (int e = 0; e < 12; ++e) { sum += xv[e]; ss += xv[e] * xv[e]; }
  for (int xm = 1; xm < 64; xm <<= 1) {
    sum += __shfl_xor(sum, xm);
    ss  += __shfl_xor(ss, xm);
  }
  __shared__ float red[8];
  const int w = t >> 6, lane = t & 63;
  if (lane == 0) { red[w] = sum; red[4 + w] = ss; }
  __syncthreads();
  sum = red[0] + red[1] + red[2] + red[3];
  ss  = red[4] + red[5] + red[6] + red[7];
  const float mean = sum * (1.f / HDIM);
  const float var = ss * (1.f / HDIM) - mean * mean;
  const float rs = rsqrtf(var + 1e-6f);
  short ov[12];
  #pragma unroll
  for (int e = 0; e < 12; ++e) {
    int c = t * 12 + e;
    float y = (xv[e] - mean) * rs * s[c] + b[c];
    ov[e] = f2bf((1.f + sc[c]) * y + sh[c]);
  }
  #pragma unroll
  for (int j = 0; j < 3; ++j) {
    s16x4 v = { ov[j*4+0], ov[j*4+1], ov[j*4+2], ov[j*4+3] };
    *(s16x4*)(out + t * 12 + j * 4) = v;
  }
}

// ---------------------------------------------------------------------------
// GEMM 128x128x64, double-buffered 2-phase pipeline (R13 config, bn-fastest).
// ---------------------------------------------------------------------------
template<int EPI>
__global__ __launch_bounds__(256, 2)
void gemm128(const short* __restrict__ A, int K, int N, int split,
             const short* __restrict__ W0, const short* __restrict__ W1,
             const float* __restrict__ b0, const float* __restrict__ b1,
             void* __restrict__ out0, void* __restrict__ out1,
             const float* __restrict__ r0, const float* __restrict__ r1,
             const float* __restrict__ g0, const float* __restrict__ g1)
{
  __shared__ __align__(16) short lds[2][16384];  // 64 KB: per buf A @0, B @8192
  const int tid = threadIdx.x;
  const int lane = tid & 63, w = tid >> 6;
  const int wr = w >> 1, wc = w & 1;
  const int l15 = lane & 15, lg = lane >> 4;

  // XCD-aware bijective remap (m204), N-tile fastest
  const int gx = gridDim.x, gy = gridDim.y;
  const int nwg = gx * gy;
  const int lin = blockIdx.y * gx + blockIdx.x;
  const int q8 = nwg >> 3, r8 = nwg & 7;
  const int xcd = lin & 7, loc = lin >> 3;
  const int nid = (xcd < r8 ? xcd * (q8 + 1) : r8 * (q8 + 1) + (xcd - r8) * q8) + loc;
  const int bn = nid % gy, bm = nid / gy;

  const bool is1 = bm >= split;
  const int m0 = bm * 128, n0 = bn * 128;
  const short* WT = is1 ? W1 : W0;
  const float* bias = is1 ? b1 : b0;
  const int nt = K >> 6;

  f32x4 acc[4][4];
  #pragma unroll
  for (int i = 0; i < 4; ++i)
    #pragma unroll
    for (int j = 0; j < 4; ++j)
      acc[i][j] = f32x4{0.f, 0.f, 0.f, 0.f};

  const int srow_b = w * 8 + (lane >> 3);     // + rep*32
  const int x7 = lane & 7;

  auto stage = [&](int tt, int b) {
    const size_t kk = (size_t)tt * 64;
    short* dst = &lds[b][0];
    #pragma unroll
    for (int rep = 0; rep < 4; ++rep) {
      const int row = rep * 32 + srow_b;
      const int lc = x7 ^ (row & 7);
      GLDS16(A + (size_t)(m0 + row) * K + kk + lc * 8, dst + rep * 2048 + w * 512);
      GLDS16(WT + (size_t)(n0 + row) * K + kk + lc * 8, dst + 8192 + rep * 2048 + w * 512);
    }
  };

  // prologue
  stage(0, 0);
  asm volatile("s_waitcnt vmcnt(0)" ::: "memory");
  __builtin_amdgcn_s_barrier();

  for (int t = 0; t < nt; ++t) {
    const int cur = t & 1;
    if (t + 1 < nt) stage(t + 1, cur ^ 1);   // issue next tile first
    const short* base = &lds[cur][0];
    #pragma unroll
    for (int ks = 0; ks < 2; ++ks) {
      const int cofs = ((ks * 4 + lg) ^ (l15 & 7)) * 8;
      s16x8 av[4], bv[4];
      #pragma unroll
      for (int mf = 0; mf < 4; ++mf)
        av[mf] = *(const s16x8*)(base + (wr * 64 + mf * 16 + l15) * 64 + cofs);
      #pragma unroll
      for (int nf = 0; nf < 4; ++nf)
        bv[nf] = *(const s16x8*)(base + 8192 + (wc * 64 + nf * 16 + l15) * 64 + cofs);
      __builtin_amdgcn_s_setprio(1);
      #pragma unroll
      for (int mf = 0; mf < 4; ++mf)
        #pragma unroll
        for (int nf = 0; nf < 4; ++nf)
          acc[mf][nf] = __builtin_amdgcn_mfma_f32_16x16x32_bf16(
              av[mf], bv[nf], acc[mf][nf], 0, 0, 0);
      __builtin_amdgcn_s_setprio(0);
    }
    if (t + 1 < nt) {
      asm volatile("s_waitcnt vmcnt(0)" ::: "memory");  // next tile landed
      __builtin_amdgcn_s_barrier();
    }
  }

  // epilogue: C frag layout col=lane&15, row=(lane>>4)*4+reg
  const int lrbase = m0 - (is1 ? split * 128 : 0);
  #pragma unroll
  for (int mf = 0; mf < 4; ++mf)
    #pragma unroll
    for (int nf = 0; nf < 4; ++nf) {
      int col = n0 + wc * 64 + nf * 16 + l15;
      float bvs = bias[col];
      #pragma unroll
      for (int r = 0; r < 4; ++r) {
        int row = lrbase + wr * 64 + mf * 16 + lg * 4 + r;
        float x = acc[mf][nf][r] + bvs;
        if constexpr (EPI == 0) {
          short* o = (short*)(is1 ? out1 : out0);
          o[(size_t)row * N + col] = f2bf(x);
        } else if constexpr (EPI == 1) {
          float g = 0.5f * x * (1.f + tanhf(0.7978845608028654f * (x + 0.044715f * x * x * x)));
          short* o = (short*)(is1 ? out1 : out0);
          o[(size_t)row * N + col] = f2bf(g);
        } else if constexpr (EPI == 2) {
          const float* resid = is1 ? r1 : r0;
          const float* gate = is1 ? g1 : g0;
          float* o = (float*)(is1 ? out1 : out0);
          o[(size_t)row * N + col] = resid[(size_t)row * N + col] + gate[col] * x;
        } else {
          const float* gate = is1 ? g1 : g0;
          float* o = (float*)(is1 ? out1 : out0);
          size_t ix = (size_t)row * N + col;
          o[ix] = o[ix] + gate[col] * x;
        }
      }
    }
}

// ---------------------------------------------------------------------------
// 4) per-(token, head) RMS norm + RoPE for q,k -> [NH][LTOT][HD] bf16
// ---------------------------------------------------------------------------
__global__ __launch_bounds__(256)
void qkvr(const short* __restrict__ qkv, const float* __restrict__ pe,
          const float* __restrict__ qn_img, const float* __restrict__ kn_img,
          const float* __restrict__ qn_txt, const float* __restrict__ kn_txt,
          short* __restrict__ Qh, short* __restrict__ Kh)
{
  const int w = threadIdx.x >> 6, lane = threadIdx.x & 63;
  const int tok = blockIdx.x * 4 + w;
  const int h = blockIdx.y;
  const float* qn = (tok < LTXT) ? qn_txt : qn_img;
  const float* kn = (tok < LTXT) ? kn_txt : kn_img;
  const size_t base = (size_t)tok * 9216 + (size_t)h * HD + lane * 2;
  const float4 p4 = *(const float4*)(pe + ((size_t)tok * 64 + lane) * 4);
  {
    s16x2 qs = *(const s16x2*)(qkv + base);
    float x0 = bf2f(qs[0]), x1 = bf2f(qs[1]);
    float sq = x0 * x0 + x1 * x1;
    for (int xm = 1; xm < 64; xm <<= 1) sq += __shfl_xor(sq, xm);
    float r = rsqrtf(sq * (1.f / HD) + 1e-6f);
    x0 = x0 * r * qn[lane * 2]; x1 = x1 * r * qn[lane * 2 + 1];
    s16x2 o = { f2bf(p4.x * x0 + p4.y * x1), f2bf(p4.z * x0 + p4.w * x1) };
    *(s16x2*)(Qh + ((size_t)h * LTOT + tok) * HD + lane * 2) = o;
  }
  {
    s16x2 ks = *(const s16x2*)(qkv + base + HDIM);
    float x0 = bf2f(ks[0]), x1 = bf2f(ks[1]);
    float sq = x0 * x0 + x1 * x1;
    for (int xm = 1; xm < 64; xm <<= 1) sq += __shfl_xor(sq, xm);
    float r = rsqrtf(sq * (1.f / HD) + 1e-6f);
    x0 = x0 * r * kn[lane * 2]; x1 = x1 * r * kn[lane * 2 + 1];
    s16x2 o = { f2bf(p4.x * x0 + p4.y * x1), f2bf(p4.z * x0 + p4.w * x1) };
    *(s16x2*)(Kh + ((size_t)h * LTOT + tok) * HD + lane * 2) = o;
  }
}

// ---------------------------------------------------------------------------
// 5) V transpose: qkv v-slice -> VT[NH][HD][LTOT] bf16. grid (LTOT/64, NH).
// ---------------------------------------------------------------------------
__global__ __launch_bounds__(256)
void vt_k(const short* __restrict__ qkv, short* __restrict__ VT)
{
  __shared__ __align__(16) short Vs[64][136];
  const int h = blockIdx.y, tok0 = blockIdx.x * 64;
  const int t = threadIdx.x;
  #pragma unroll
  for (int rep = 0; rep < 4; ++rep) {
    int idx = rep * 256 + t;
    int tk = idx >> 4, oct = idx & 15;
    *(s16x8*)(&Vs[tk][oct * 8]) =
        *(const s16x8*)(qkv + (size_t)(tok0 + tk) * 9216 + 6144 + (size_t)h * HD + oct * 8);
  }
  __syncthreads();
  #pragma unroll
  for (int rep = 0; rep < 4; ++rep) {
    int idx = rep * 256 + t;
    int d = idx >> 3, tg = idx & 7;
    s16x8 o;
    #pragma unroll
    for (int j = 0; j < 8; ++j) o[j] = Vs[tg * 8 + j][d];
    *(s16x8*)(VT + ((size_t)h * HD + d) * LTOT + tok0 + tg * 8) = o;
  }
}

// ---------------------------------------------------------------------------
// 6) Flash attention, static softmax + cooperative K staging (R12 config)
// + T5 setprio around MFMA clusters.
// ---------------------------------------------------------------------------
__global__ __launch_bounds__(256, 3)
void attn_k(const short* __restrict__ Qh, const short* __restrict__ Kh,
            const short* __restrict__ VT, short* __restrict__ out)
{
  __shared__ __align__(16) short Ks[2][8192];   // [buf][64 keys][128 d] swizzled
  __shared__ __align__(16) short Ps[4][32][72];
  const int t = threadIdx.x, lane = t & 63, w = t >> 6;
  const int l15 = lane & 15, lg = lane >> 4;
  const int lin = blockIdx.y * gridDim.x + blockIdx.x;
  const int xcd = lin & 7, j = lin >> 3;
  const int h = xcd * 3 + j / 18;
  const int qrow = (j % 18) * 128 + w * 32;

  s16x8 qf[2][4];
  #pragma unroll
  for (int mf = 0; mf < 2; ++mf)
    #pragma unroll
    for (int ks = 0; ks < 4; ++ks)
      qf[mf][ks] = *(const s16x8*)(Qh + ((size_t)h * LTOT + qrow + mf * 16 + l15) * HD + ks * 32 + lg * 8);

  f32x4 O[2][8];
  #pragma unroll
  for (int mf = 0; mf < 2; ++mf)
    #pragma unroll
    for (int dt = 0; dt < 8; ++dt) O[mf][dt] = f32x4{0.f, 0.f, 0.f, 0.f};
  f32x4 den[2];
  den[0] = f32x4{0.f, 0.f, 0.f, 0.f};
  den[1] = f32x4{0.f, 0.f, 0.f, 0.f};

  const float scl = 0.08838834764831845f;  // 1/sqrt(128)

  auto stageK = [&](int kt, int b) {
    const int k0 = kt * 64;
    #pragma unroll
    for (int it = 0; it < 4; ++it) {
      const int idx = it * 256 + w * 64 + lane;
      const int row = idx >> 4, p = idx & 15;
      const int l = p ^ (row & 15);
      GLDS16(Kh + ((size_t)h * LTOT + k0 + row) * HD + l * 8,
             &Ks[b][(it * 256 + w * 64) * 8]);
    }
  };

  stageK(0, 0);
  asm volatile("s_waitcnt vmcnt(0)" ::: "memory");
  __builtin_amdgcn_s_barrier();

  for (int kt = 0; kt < LTOT / 64; ++kt) {
    const int k0 = kt * 64;
    const int b = kt & 1;
    if (kt + 1 < LTOT / 64) stageK(kt + 1, b ^ 1);
    f32x4 S[2][4];
    #pragma unroll
    for (int mf = 0; mf < 2; ++mf)
      #pragma unroll
      for (int jt = 0; jt < 4; ++jt) S[mf][jt] = f32x4{0.f, 0.f, 0.f, 0.f};
    __builtin_amdgcn_s_setprio(1);
    #pragma unroll
    for (int ks = 0; ks < 4; ++ks)
      #pragma unroll
      for (int jt = 0; jt < 4; ++jt) {
        const int row = jt * 16 + l15;
        s16x8 kf = *(const s16x8*)(&Ks[b][row * 128 + ((ks * 4 + lg) ^ l15) * 8]);
        S[0][jt] = __builtin_amdgcn_mfma_f32_16x16x32_bf16(qf[0][ks], kf, S[0][jt], 0, 0, 0);
        S[1][jt] = __builtin_amdgcn_mfma_f32_16x16x32_bf16(qf[1][ks], kf, S[1][jt], 0, 0, 0);
      }
    __builtin_amdgcn_s_setprio(0);
    #pragma unroll
    for (int mf = 0; mf < 2; ++mf)
      #pragma unroll
      for (int jt = 0; jt < 4; ++jt)
        #pragma unroll
        for (int r = 0; r < 4; ++r) {
          float p = __expf(S[mf][jt][r] * scl);
          den[mf][r] += p;
          Ps[w][mf * 16 + lg * 4 + r][jt * 16 + l15] = f2bf(p);
        }
    asm volatile("s_waitcnt lgkmcnt(0)" ::: "memory");
    __builtin_amdgcn_sched_barrier(0);
    #pragma unroll
    for (int kk2 = 0; kk2 < 2; ++kk2) {
      s16x8 pf0 = *(const s16x8*)(&Ps[w][l15][kk2 * 32 + lg * 8]);
      s16x8 pf1 = *(const s16x8*)(&Ps[w][16 + l15][kk2 * 32 + lg * 8]);
      __builtin_amdgcn_s_setprio(1);
      #pragma unroll
      for (int dt = 0; dt < 8; ++dt) {
        s16x8 vf = *(const s16x8*)(VT + ((size_t)h * HD + dt * 16 + l15) * LTOT + k0 + kk2 * 32 + lg * 8);
        O[0][dt] = __builtin_amdgcn_mfma_f32_16x16x32_bf16(pf0, vf, O[0][dt], 0, 0, 0);
        O[1][dt] = __builtin_amdgcn_mfma_f32_16x16x32_bf16(pf1, vf, O[1][dt], 0, 0, 0);
      }
      __builtin_amdgcn_s_setprio(0);
    }
    asm volatile("s_waitcnt lgkmcnt(0)" ::: "memory");
    __builtin_amdgcn_sched_barrier(0);
    asm volatile("s_waitcnt vmcnt(0)" ::: "memory");
    __builtin_amdgcn_s_barrier();
  }

  #pragma unroll
  for (int mf = 0; mf < 2; ++mf)
    for (int xm = 1; xm < 16; xm <<= 1)
      #pragma unroll
      for (int r = 0; r < 4; ++r)
        den[mf][r] += __shfl_xor(den[mf][r], xm);

  #pragma unroll
  for (int mf = 0; mf < 2; ++mf) {
    f32x4 inv;
    #pragma unroll
    for (int r = 0; r < 4; ++r) inv[r] = 1.f / den[mf][r];
    #pragma unroll
    for (int dt = 0; dt < 8; ++dt) {
      f32x4 o = O[mf][dt] * inv;
      #pragma unroll
      for (int r = 0; r < 4; ++r)
        out[(size_t)(qrow + mf * 16 + lg * 4 + r) * HDIM + (size_t)h * HD + dt * 16 + l15] = f2bf(o[r]);
    }
  }
}

// ---------------------------------------------------------------------------
extern "C" void kernel_launch(void* const* d_in, const int* in_sizes, int n_in,
                              void* d_out, int out_size, void* d_ws, size_t ws_size,
                              hipStream_t stream)
{
  (void)in_sizes; (void)n_in; (void)out_size;
  const float* img = (const float*)d_in[0];
  const float* txt = (const float*)d_in[1];
  const float* vec = (const float*)d_in[2];
  const float* pe  = (const float*)d_in[3];
  const float* Pi[16]; const float* Pt[16];
  for (int i = 0; i < 16; ++i) Pi[i] = (const float*)d_in[4 + i];
  for (int i = 0; i < 16; ++i) Pt[i] = (const float*)d_in[20 + i];
  // 0 mod_w,1 mod_b,2 ln1_s,3 ln1_b,4 qkv_w,5 qkv_b,6 qn,7 kn,8 proj_w,
  // 9 proj_b,10 ln2_s,11 ln2_b,12 mlp_w1,13 mlp_b1,14 mlp_w2,15 mlp_b2

  char* ws = (char*)d_ws;
  float* MODI = (float*)(ws + 0);
  float* MODT = (float*)(ws + 73728);
  short* XMI  = (short*)(ws + 147456);        // [2304][3072] bf16 img-first
  short* XMT  = (short*)(ws + 12730368);
  short* QKV  = (short*)(ws + 14303232);      // [2304][9216] bf16, txt-first rows
  short* QHh  = (short*)(ws + 56770560);      // [24][2304][128]
  short* KHh  = (short*)(ws + 70926336);
  short* VTt  = (short*)(ws + 85082112);      // [24][128][2304]
  short* ATT  = (short*)(ws + 99237888);      // [2304][3072] txt-first rows
  short* H1   = (short*)(ws + 14303232);      // reuse QKV+QH region: [2304][12288] img-first
  short* WTA  = (short*)(ws + 113393664);     // 75.5 MB transposed-weight buf A
  short* WTB  = (short*)(ws + 188891136);     // 75.5 MB transposed-weight buf B
  if (ws_size < (size_t)264388608) return;
  float* outI = (float*)d_out;
  float* outT = outI + (size_t)LIMG * HDIM;

  // 1) modulation vectors
  mod_gemv<<<dim3(144, 2), 256, 0, stream>>>(vec, Pi[0], Pi[1], Pt[0], Pt[1], MODI, MODT);
  // 2) LN1 + modulate
  ln_mod<<<dim3(LTOT), 256, 0, stream>>>(img, txt, LIMG, Pi[2], Pi[3], Pt[2], Pt[3],
                                         MODI, MODT, 0, 1, XMI, XMT);
  // 3) QKV: convert weights (merged img+txt), merged gemm (split=16)
  wconv2<<<dim3(48, 144, 2), 256, 0, stream>>>(Pi[4], WTA, Pt[4], WTB, HDIM, 3 * HDIM);
  gemm128<0><<<dim3(18, 72), 256, 0, stream>>>(XMI, HDIM, 3 * HDIM, 16,
      WTA, WTB, Pi[5], Pt[5],
      QKV + (size_t)LTXT * 9216, QKV, nullptr, nullptr, nullptr, nullptr);
  // 4) RMS + RoPE
  qkvr<<<dim3(LTOT / 4, NHEADS), 256, 0, stream>>>(QKV, pe, Pi[6], Pi[7], Pt[6], Pt[7], QHh, KHh);
  // 5) V transpose
  vt_k<<<dim3(LTOT / 64, NHEADS), 256, 0, stream>>>(QKV, VTt);
  // 6) attention (head-grouped XCD mapping, static softmax, K staged)
  attn_k<<<dim3(18, 24), 256, 0, stream>>>(QHh, KHh, VTt, ATT);
  // 7) proj + gated residual -> d_out (ATT txt-first, split=2: stream0=txt)
  wconv2<<<dim3(48, 48, 2), 256, 0, stream>>>(Pt[8], WTA, Pi[8], WTB, HDIM, HDIM);
  gemm128<2><<<dim3(18, 24), 256, 0, stream>>>(ATT, HDIM, HDIM, 2,
      WTA, WTB, Pt[9], Pi[9], outT, outI, txt, img,
      MODT + 2 * HDIM, MODI + 2 * HDIM);
  // 8) LN2 + modulate
  ln_mod<<<dim3(LTOT), 256, 0, stream>>>(outI, outT, LIMG, Pi[10], Pi[11], Pt[10], Pt[11],
                                         MODI, MODT, 3, 4, XMI, XMT);
  // 9) MLP1 + gelu (split=16) -> H1 img-first
  wconv2<<<dim3(48, 192, 2), 256, 0, stream>>>(Pi[12], WTA, Pt[12], WTB, HDIM, MLPD);
  gemm128<1><<<dim3(18, 96), 256, 0, stream>>>(XMI, HDIM, MLPD, 16,
      WTA, WTB, Pi[13], Pt[13],
      H1, H1 + (size_t)LIMG * MLPD, nullptr, nullptr, nullptr, nullptr);
  // 10) MLP2 + gated residual add (split=16)
  wconv2<<<dim3(192, 48, 2), 256, 0, stream>>>(Pi[14], WTA, Pt[14], WTB, MLPD, HDIM);
  gemm128<3><<<dim3(18, 24), 256, 0, stream>>>(H1, MLPD, HDIM, 16,
      WTA, WTB, Pi[15], Pt[15], outI, outT, nullptr, nullptr,
      MODI + 5 * HDIM, MODT + 5 * HDIM);
}